// Round 1
// baseline (963.970 us; speedup 1.0000x reference)
//
#include <hip/hip_runtime.h>
#include <hip/hip_bf16.h>
#include <stdint.h>

// Problem constants (reference: B=4, T=512, H=32, N=64, D=2048)
#define B_ 4
#define T_ 512
#define H_ 32
#define N_ 64
#define D_ 2048
#define M_ (B_*T_)   // 2048 rows of y

typedef __attribute__((ext_vector_type(4))) float f32x4;
typedef __attribute__((ext_vector_type(8))) short short8;  // 8 bf16 = 4 VGPRs

__device__ __forceinline__ float rl(float v, int l) {
    // wave-uniform broadcast: lane l's value -> SGPR
    return __int_as_float(__builtin_amdgcn_readlane(__float_as_int(v), l));
}

// ---------------------------------------------------------------------------
// Kernel 1: dequant weights int32 -> bf16 (ints in [-128,127] are exact bf16).
// scale[o] is applied in the GEMM epilogue in fp32 (exact).
// ---------------------------------------------------------------------------
__global__ __launch_bounds__(256) void conv_w(const int* __restrict__ q,
                                              __hip_bfloat16* __restrict__ o) {
    int i = (blockIdx.x * 256 + threadIdx.x) * 4;
    int4 qi = *(const int4*)(q + i);
    __hip_bfloat16 t[4];
    t[0] = __float2bfloat16((float)qi.x);
    t[1] = __float2bfloat16((float)qi.y);
    t[2] = __float2bfloat16((float)qi.z);
    t[3] = __float2bfloat16((float)qi.w);
    *(uint2*)(o + i) = *(uint2*)t;
}

// ---------------------------------------------------------------------------
// Kernel 2: WKV-7 scan. One wave per (b,h). lane = state row i, S[i,:] in VGPRs.
// Per step: shared per-channel vectors live lane-j-wise; j-loop broadcasts via
// v_readlane (constant lane after full unroll). sa uses OLD state; y uses NEW.
//   d = exp(-exp(w)); kk = k*rsqrt(sum k^2 + 1e-12); a=-kk; b=kk*sigmoid(iclr)
//   sa_i = S[i,:].a ;  S[i,j] = S*d_j + sa_i*b_j + v_i*k_j ;  y_i = S[i,:].r
// Writes y as bf16 into ws laid out [M=B*T, D] for the GEMM.
// ---------------------------------------------------------------------------
__global__ __launch_bounds__(64, 1) void wkv_scan(
    const float* __restrict__ r, const float* __restrict__ w,
    const float* __restrict__ k, const float* __restrict__ v,
    const float* __restrict__ iclr, __hip_bfloat16* __restrict__ y) {
    const int bh = blockIdx.x;      // 0..127
    const int b = bh >> 5;          // / H
    const int h = bh & 31;          // % H
    const int lane = threadIdx.x;   // row i

    float S[N_];
#pragma unroll
    for (int j = 0; j < N_; ++j) S[j] = 0.f;

    size_t idx = ((size_t)b * T_ * H_ + h) * N_ + lane;   // t=0 element
    const size_t step = (size_t)H_ * N_;                  // stride per t
    size_t orow = ((size_t)b * T_) * D_ + h * N_ + lane;  // y output index

    // preload t=0 (prefetch next inside loop to hide load latency)
    float rv = r[idx], wv = w[idx], kv = k[idx], vv = v[idx], av = iclr[idx];

    for (int t = 0; t < T_; ++t) {
        float rn = 0.f, wn = 0.f, kn = 0.f, vn = 0.f, an = 0.f;
        if (t + 1 < T_) {
            size_t ix2 = idx + step;
            rn = r[ix2]; wn = w[ix2]; kn = k[ix2]; vn = v[ix2]; an = iclr[ix2];
        }

        float dec = expf(-expf(wv));            // per-channel decay (this lane's j)
        float ss = kv * kv;
#pragma unroll
        for (int m = 1; m < 64; m <<= 1) ss += __shfl_xor(ss, m, 64);
        float kk = kv * rsqrtf(ss + 1e-12f);
        float sig = 1.f / (1.f + expf(-av));
        float bb = kk * sig;                    // b_j

        // sa = -(S . kk)  (old state), 4 accumulators for ILP
        float g0 = 0.f, g1 = 0.f, g2 = 0.f, g3 = 0.f;
#pragma unroll
        for (int j = 0; j < N_; j += 4) {
            g0 = fmaf(S[j    ], rl(kk, j    ), g0);
            g1 = fmaf(S[j + 1], rl(kk, j + 1), g1);
            g2 = fmaf(S[j + 2], rl(kk, j + 2), g2);
            g3 = fmaf(S[j + 3], rl(kk, j + 3), g3);
        }
        float sa = -((g0 + g1) + (g2 + g3));

        float y0 = 0.f, y1 = 0.f, y2 = 0.f, y3 = 0.f;
#pragma unroll
        for (int j = 0; j < N_; j += 4) {
            {
                float t0 = fmaf(sa, rl(bb, j), vv * rl(kv, j));
                S[j] = fmaf(S[j], rl(dec, j), t0);
                y0 = fmaf(S[j], rl(rv, j), y0);
            }
            {
                float t0 = fmaf(sa, rl(bb, j + 1), vv * rl(kv, j + 1));
                S[j + 1] = fmaf(S[j + 1], rl(dec, j + 1), t0);
                y1 = fmaf(S[j + 1], rl(rv, j + 1), y1);
            }
            {
                float t0 = fmaf(sa, rl(bb, j + 2), vv * rl(kv, j + 2));
                S[j + 2] = fmaf(S[j + 2], rl(dec, j + 2), t0);
                y2 = fmaf(S[j + 2], rl(rv, j + 2), y2);
            }
            {
                float t0 = fmaf(sa, rl(bb, j + 3), vv * rl(kv, j + 3));
                S[j + 3] = fmaf(S[j + 3], rl(dec, j + 3), t0);
                y3 = fmaf(S[j + 3], rl(rv, j + 3), y3);
            }
        }
        y[orow] = __float2bfloat16((y0 + y1) + (y2 + y3));

        orow += D_;
        idx += step;
        rv = rn; wv = wn; kv = kn; vv = vn; av = an;
    }
}

// ---------------------------------------------------------------------------
// Kernel 3: C[m,o] = scale[o] * sum_d Y[m,d] * Wq[o,d]   (B^T-layout GEMM)
// 128x128 tile, BK=64, 4 waves; wave quadrant 64x64 = 4x4 MFMA 16x16x32 bf16.
// Register staging this round (global_load_lds upgrade deferred).
// ---------------------------------------------------------------------------
__global__ __launch_bounds__(256, 1) void gemm_bt(
    const __hip_bfloat16* __restrict__ A,   // [M, K] y bf16
    const __hip_bfloat16* __restrict__ Bq,  // [N, K] weights bf16
    const float* __restrict__ scale,        // [N]
    float* __restrict__ C) {                // [M, N] fp32
    const int K = D_;
    __shared__ __align__(16) ushort As[128 * 64];
    __shared__ __align__(16) ushort Bs[128 * 64];

    const int tid = threadIdx.x;
    const int lane = tid & 63;
    const int wave = tid >> 6;
    const int wr = wave >> 1, wc = wave & 1;     // wave quadrant in 128x128
    const int m0 = blockIdx.x * 128;
    const int n0 = blockIdx.y * 128;

    const int srow = tid >> 3;                   // staging: 32 rows/iter
    const int scol = (tid & 7) * 8;              // 8 bf16 (16B) per thread
    const int ml = lane & 15;                    // m (or n) within 16-tile
    const int kq = (lane >> 4) * 8;              // k-offset of this quad

    f32x4 acc[4][4] = {};

    for (int k0 = 0; k0 < K; k0 += 64) {
#pragma unroll
        for (int it = 0; it < 4; ++it) {
            int rowi = it * 32 + srow;
            uint4 a = *(const uint4*)(A  + (size_t)(m0 + rowi) * K + k0 + scol);
            uint4 bv = *(const uint4*)(Bq + (size_t)(n0 + rowi) * K + k0 + scol);
            *(uint4*)(&As[rowi * 64 + scol]) = a;
            *(uint4*)(&Bs[rowi * 64 + scol]) = bv;
        }
        __syncthreads();
#pragma unroll
        for (int ks = 0; ks < 2; ++ks) {
            short8 af[4], bf[4];
#pragma unroll
            for (int tm = 0; tm < 4; ++tm)
                af[tm] = *(const short8*)(&As[(wr * 64 + tm * 16 + ml) * 64 + ks * 32 + kq]);
#pragma unroll
            for (int tn = 0; tn < 4; ++tn)
                bf[tn] = *(const short8*)(&Bs[(wc * 64 + tn * 16 + ml) * 64 + ks * 32 + kq]);
#pragma unroll
            for (int tm = 0; tm < 4; ++tm)
#pragma unroll
                for (int tn = 0; tn < 4; ++tn)
                    acc[tm][tn] = __builtin_amdgcn_mfma_f32_16x16x32_bf16(
                        af[tm], bf[tn], acc[tm][tn], 0, 0, 0);
        }
        __syncthreads();
    }

    // epilogue: C/D layout col=lane&15, row=(lane>>4)*4+reg  [m89-verified]
#pragma unroll
    for (int tn = 0; tn < 4; ++tn) {
        int gn = n0 + wc * 64 + tn * 16 + ml;
        float sc = scale[gn];
#pragma unroll
        for (int tm = 0; tm < 4; ++tm) {
            int gm = m0 + wr * 64 + tm * 16 + (lane >> 4) * 4;
#pragma unroll
            for (int rg = 0; rg < 4; ++rg)
                C[(size_t)(gm + rg) * D_ + gn] = acc[tm][tn][rg] * sc;
        }
    }
}

// ---------------------------------------------------------------------------
extern "C" void kernel_launch(void* const* d_in, const int* in_sizes, int n_in,
                              void* d_out, int out_size, void* d_ws, size_t ws_size,
                              hipStream_t stream) {
    (void)in_sizes; (void)n_in; (void)out_size; (void)ws_size;
    const float* r    = (const float*)d_in[0];
    const float* w    = (const float*)d_in[1];
    const float* k    = (const float*)d_in[2];
    const float* v    = (const float*)d_in[3];
    const float* ic   = (const float*)d_in[4];
    const int*   wq   = (const int*)d_in[5];
    const float* sc   = (const float*)d_in[6];
    float* out = (float*)d_out;

    // workspace: [0, 8MB) y bf16 [M,D]; [8MB, 16MB) weights bf16 [D,D]
    __hip_bfloat16* yb = (__hip_bfloat16*)d_ws;
    __hip_bfloat16* wb = (__hip_bfloat16*)((char*)d_ws + (size_t)M_ * D_ * sizeof(__hip_bfloat16));

    conv_w<<<dim3((D_ * D_) / (256 * 4)), dim3(256), 0, stream>>>(wq, wb);
    wkv_scan<<<dim3(B_ * H_), dim3(64), 0, stream>>>(r, w, k, v, ic, yb);
    gemm_bt<<<dim3(M_ / 128, D_ / 128), dim3(256), 0, stream>>>(yb, wb, sc, out);
}

// Round 2
// 571.613 us; speedup vs baseline: 1.6864x; 1.6864x over previous
//
#include <hip/hip_runtime.h>
#include <hip/hip_bf16.h>
#include <stdint.h>

#define B_ 4
#define T_ 512
#define H_ 32
#define N_ 64
#define D_ 2048
#define M_ (B_*T_)

typedef __attribute__((ext_vector_type(4))) float f32x4;
typedef __attribute__((ext_vector_type(8))) short short8;

// ---------------------------------------------------------------------------
// Kernel 1: dequant weights int32 -> bf16 (ints in [-128,127] exact in bf16).
// ---------------------------------------------------------------------------
__global__ __launch_bounds__(256) void conv_w(const int* __restrict__ q,
                                              __hip_bfloat16* __restrict__ o) {
    int i = (blockIdx.x * 256 + threadIdx.x) * 4;
    int4 qi = *(const int4*)(q + i);
    __hip_bfloat16 t[4];
    t[0] = __float2bfloat16((float)qi.x);
    t[1] = __float2bfloat16((float)qi.y);
    t[2] = __float2bfloat16((float)qi.z);
    t[3] = __float2bfloat16((float)qi.w);
    *(uint2*)(o + i) = *(uint2*)t;
}

// ---------------------------------------------------------------------------
// Kernel 2: precompute per-(b,t,h,channel) vectors:
//   dec = exp(-exp(w)); kk = k*rsqrt(sum_j k^2 + 1e-12); bb = kk*sigmoid(iclr)
// One wave per (b,t,h); lane = channel. Memory-bound (~100 MB total).
// ---------------------------------------------------------------------------
__global__ __launch_bounds__(256) void precomp(
    const float* __restrict__ w, const float* __restrict__ k,
    const float* __restrict__ iclr,
    float* __restrict__ dec, float* __restrict__ kk, float* __restrict__ bb) {
    int g = blockIdx.x * 4 + (threadIdx.x >> 6);   // bth index
    int lane = threadIdx.x & 63;
    size_t off = (size_t)g * 64 + lane;
    float wv = w[off], kv = k[off], av = iclr[off];
    float d = expf(-expf(wv));
    float ss = kv * kv;
#pragma unroll
    for (int m = 1; m < 64; m <<= 1) ss += __shfl_xor(ss, m, 64);
    float kkv = kv * rsqrtf(ss + 1e-12f);
    float bbv = kkv * (1.f / (1.f + expf(-av)));
    dec[off] = d; kk[off] = kkv; bb[off] = bbv;
}

// ---------------------------------------------------------------------------
// Kernel 3: WKV-7 scan, 4 waves per (b,h) as 4 INDEPENDENT single-wave blocks.
// lane = (row_local = lane&15, jg = lane>>4); lane owns S[row, jg*16..jg*16+16).
// Per step: contiguous float4 slice loads of dec/kk/bb/k/r (double-buffered),
// sa & y reductions via shfl_xor(16,32). 512 blocks -> 2 waves/CU.
// ---------------------------------------------------------------------------
#define LD4(dst, p) { const f32x4* _q = (const f32x4*)(p); \
    dst[0]=_q[0]; dst[1]=_q[1]; dst[2]=_q[2]; dst[3]=_q[3]; }

__global__ __launch_bounds__(64, 1) void wkv_scan(
    const float* __restrict__ r, const float* __restrict__ k,
    const float* __restrict__ v, const float* __restrict__ dec,
    const float* __restrict__ kk, const float* __restrict__ bb,
    __hip_bfloat16* __restrict__ y) {
    const int bh = blockIdx.x >> 2;
    const int wv = blockIdx.x & 3;
    const int b = bh >> 5, h = bh & 31;
    const int lane = threadIdx.x;
    const int rlcl = lane & 15, jg = lane >> 4;
    const int row = wv * 16 + rlcl;         // state row i this lane serves
    const int jb = jg * 16;                 // j-slice base

    float S[16];
#pragma unroll
    for (int j = 0; j < 16; ++j) S[j] = 0.f;

    size_t base = ((size_t)b * T_ * H_ + h) * 64;
    const size_t step = (size_t)H_ * 64;
    size_t orow = ((size_t)b * T_) * D_ + h * 64 + row;

    f32x4 Rc[4], Kc[4], Dc[4], Ac[4], Bc[4];
    float vc;
    LD4(Rc, r   + base + jb); LD4(Kc, k  + base + jb);
    LD4(Dc, dec + base + jb); LD4(Ac, kk + base + jb);
    LD4(Bc, bb  + base + jb); vc = v[base + row];

    for (int t = 0; t < T_; ++t) {
        size_t nb = base + ((t + 1 < T_) ? step : 0);   // clamped prefetch
        f32x4 Rn[4], Kn[4], Dn[4], An[4], Bn[4];
        LD4(Rn, r   + nb + jb); LD4(Kn, k  + nb + jb);
        LD4(Dn, dec + nb + jb); LD4(An, kk + nb + jb);
        LD4(Bn, bb  + nb + jb);
        float vn = v[nb + row];

        // sa_i = -(S_old . kk) over this lane's 16 j, then reduce across jg
        float a0 = 0.f, a1 = 0.f, a2 = 0.f, a3 = 0.f;
#pragma unroll
        for (int q = 0; q < 4; ++q) {
            a0 = fmaf(S[q*4+0], Ac[q][0], a0);
            a1 = fmaf(S[q*4+1], Ac[q][1], a1);
            a2 = fmaf(S[q*4+2], Ac[q][2], a2);
            a3 = fmaf(S[q*4+3], Ac[q][3], a3);
        }
        float sum = (a0 + a1) + (a2 + a3);
        sum += __shfl_xor(sum, 16, 64);
        sum += __shfl_xor(sum, 32, 64);
        float sa = -sum;

        // S[i,j] = S*dec_j + sa_i*bb_j + v_i*k_j ;  y_i partial = S_new . r
        float y0 = 0.f, y1 = 0.f, y2 = 0.f, y3 = 0.f;
#pragma unroll
        for (int q = 0; q < 4; ++q) {
            {
                float t0 = fmaf(sa, Bc[q][0], vc * Kc[q][0]);
                S[q*4+0] = fmaf(S[q*4+0], Dc[q][0], t0);
                y0 = fmaf(S[q*4+0], Rc[q][0], y0);
            }
            {
                float t0 = fmaf(sa, Bc[q][1], vc * Kc[q][1]);
                S[q*4+1] = fmaf(S[q*4+1], Dc[q][1], t0);
                y1 = fmaf(S[q*4+1], Rc[q][1], y1);
            }
            {
                float t0 = fmaf(sa, Bc[q][2], vc * Kc[q][2]);
                S[q*4+2] = fmaf(S[q*4+2], Dc[q][2], t0);
                y2 = fmaf(S[q*4+2], Rc[q][2], y2);
            }
            {
                float t0 = fmaf(sa, Bc[q][3], vc * Kc[q][3]);
                S[q*4+3] = fmaf(S[q*4+3], Dc[q][3], t0);
                y3 = fmaf(S[q*4+3], Rc[q][3], y3);
            }
        }
        float ys = (y0 + y1) + (y2 + y3);
        ys += __shfl_xor(ys, 16, 64);
        ys += __shfl_xor(ys, 32, 64);
        if (jg == 0) y[orow] = __float2bfloat16(ys);

        orow += D_;
        base += step;
#pragma unroll
        for (int q = 0; q < 4; ++q) {
            Rc[q] = Rn[q]; Kc[q] = Kn[q]; Dc[q] = Dn[q];
            Ac[q] = An[q]; Bc[q] = Bn[q];
        }
        vc = vn;
    }
}

// ---------------------------------------------------------------------------
// Kernel 4: C[m,o] = scale[o] * sum_d Y[m,d] * Wq[o,d]  (B^T GEMM)
// 128x128 tile, BK=64, 4 waves; global_load_lds width-16 staging (m97).
// ---------------------------------------------------------------------------
__device__ __forceinline__ void gload_lds16(const __hip_bfloat16* g, ushort* l) {
    __builtin_amdgcn_global_load_lds(
        (const __attribute__((address_space(1))) unsigned int*)g,
        (__attribute__((address_space(3))) unsigned int*)l, 16, 0, 0);
}

__global__ __launch_bounds__(256, 1) void gemm_bt(
    const __hip_bfloat16* __restrict__ A,   // [M, K]
    const __hip_bfloat16* __restrict__ Bq,  // [N, K]
    const float* __restrict__ scale,        // [N]
    float* __restrict__ C) {                // [M, N]
    const int K = D_;
    __shared__ __align__(16) ushort As[128 * 64];
    __shared__ __align__(16) ushort Bs[128 * 64];

    const int tid = threadIdx.x;
    const int lane = tid & 63;
    const int wave = tid >> 6;
    const int wr = wave >> 1, wc = wave & 1;
    const int m0 = blockIdx.x * 128;
    const int n0 = blockIdx.y * 128;

    const int srow8 = lane >> 3;            // 0..7 within an 8-row chunk
    const int scol8 = (lane & 7) * 8;       // bf16 col (16B per lane)
    const int ml = lane & 15;
    const int kq = (lane >> 4) * 8;

    f32x4 acc[4][4] = {};

    for (int k0 = 0; k0 < K; k0 += 64) {
#pragma unroll
        for (int c = 0; c < 4; ++c) {
            int rbase = wave * 32 + c * 8;          // 8 rows per call
            int row = rbase + srow8;
            gload_lds16(A  + (size_t)(m0 + row) * K + k0 + scol8, &As[rbase * 64]);
            gload_lds16(Bq + (size_t)(n0 + row) * K + k0 + scol8, &Bs[rbase * 64]);
        }
        __syncthreads();
#pragma unroll
        for (int ks = 0; ks < 2; ++ks) {
            short8 af[4], bf[4];
#pragma unroll
            for (int tm = 0; tm < 4; ++tm)
                af[tm] = *(const short8*)(&As[(wr * 64 + tm * 16 + ml) * 64 + ks * 32 + kq]);
#pragma unroll
            for (int tn = 0; tn < 4; ++tn)
                bf[tn] = *(const short8*)(&Bs[(wc * 64 + tn * 16 + ml) * 64 + ks * 32 + kq]);
#pragma unroll
            for (int tm = 0; tm < 4; ++tm)
#pragma unroll
                for (int tn = 0; tn < 4; ++tn)
                    acc[tm][tn] = __builtin_amdgcn_mfma_f32_16x16x32_bf16(
                        af[tm], bf[tn], acc[tm][tn], 0, 0, 0);
        }
        __syncthreads();
    }

    // epilogue: C/D layout col=lane&15, row=(lane>>4)*4+reg
#pragma unroll
    for (int tn = 0; tn < 4; ++tn) {
        int gn = n0 + wc * 64 + tn * 16 + ml;
        float sc = scale[gn];
#pragma unroll
        for (int tm = 0; tm < 4; ++tm) {
            int gm = m0 + wr * 64 + tm * 16 + (lane >> 4) * 4;
#pragma unroll
            for (int rg = 0; rg < 4; ++rg)
                C[(size_t)(gm + rg) * D_ + gn] = acc[tm][tn][rg] * sc;
        }
    }
}

// ---------------------------------------------------------------------------
extern "C" void kernel_launch(void* const* d_in, const int* in_sizes, int n_in,
                              void* d_out, int out_size, void* d_ws, size_t ws_size,
                              hipStream_t stream) {
    (void)in_sizes; (void)n_in; (void)out_size; (void)ws_size;
    const float* r  = (const float*)d_in[0];
    const float* w  = (const float*)d_in[1];
    const float* k  = (const float*)d_in[2];
    const float* v  = (const float*)d_in[3];
    const float* ic = (const float*)d_in[4];
    const int*   wq = (const int*)d_in[5];
    const float* sc = (const float*)d_in[6];
    float* out = (float*)d_out;

    // ws layout: yb 8.4MB | wb 8.4MB | dec 16.8MB | kk 16.8MB | bb 16.8MB
    char* p = (char*)d_ws;
    __hip_bfloat16* yb = (__hip_bfloat16*)p;            p += (size_t)M_ * D_ * 2;
    __hip_bfloat16* wb = (__hip_bfloat16*)p;            p += (size_t)D_ * D_ * 2;
    float* dec = (float*)p;                             p += (size_t)B_*T_*H_*N_*4;
    float* kk  = (float*)p;                             p += (size_t)B_*T_*H_*N_*4;
    float* bb  = (float*)p;

    conv_w <<<dim3((D_ * D_) / (256 * 4)), dim3(256), 0, stream>>>(wq, wb);
    precomp<<<dim3(B_ * T_ * H_ / 4), dim3(256), 0, stream>>>(w, k, ic, dec, kk, bb);
    wkv_scan<<<dim3(B_ * H_ * 4), dim3(64), 0, stream>>>(r, k, v, dec, kk, bb, yb);
    gemm_bt<<<dim3(M_ / 128, D_ / 128), dim3(256), 0, stream>>>(yb, wb, sc, out);
}

// Round 3
// 438.424 us; speedup vs baseline: 2.1987x; 1.3038x over previous
//
#include <hip/hip_runtime.h>
#include <hip/hip_bf16.h>
#include <stdint.h>

#define B_ 4
#define T_ 512
#define H_ 32
#define N_ 64
#define D_ 2048
#define M_ (B_*T_)

typedef __attribute__((ext_vector_type(4))) float f32x4;
typedef __attribute__((ext_vector_type(8))) short short8;

// ---------------------------------------------------------------------------
// Kernel 1: dequant weights int32 -> bf16 (ints in [-128,127] exact in bf16).
// ---------------------------------------------------------------------------
__global__ __launch_bounds__(256) void conv_w(const int* __restrict__ q,
                                              __hip_bfloat16* __restrict__ o) {
    int i = (blockIdx.x * 256 + threadIdx.x) * 4;
    int4 qi = *(const int4*)(q + i);
    __hip_bfloat16 t[4];
    t[0] = __float2bfloat16((float)qi.x);
    t[1] = __float2bfloat16((float)qi.y);
    t[2] = __float2bfloat16((float)qi.z);
    t[3] = __float2bfloat16((float)qi.w);
    *(uint2*)(o + i) = *(uint2*)t;
}

// ---------------------------------------------------------------------------
// Kernel 2: precompute per-(b,t,h,channel):
//   dec = exp(-exp(w)); kk = k*rsqrt(sum_j k^2 + 1e-12); bb = kk*sigmoid(iclr)
// ---------------------------------------------------------------------------
__global__ __launch_bounds__(256) void precomp(
    const float* __restrict__ w, const float* __restrict__ k,
    const float* __restrict__ iclr,
    float* __restrict__ dec, float* __restrict__ kk, float* __restrict__ bb) {
    int g = blockIdx.x * 4 + (threadIdx.x >> 6);   // bth index
    int lane = threadIdx.x & 63;
    size_t off = (size_t)g * 64 + lane;
    float wv = w[off], kv = k[off], av = iclr[off];
    float d = expf(-expf(wv));
    float ss = kv * kv;
#pragma unroll
    for (int m = 1; m < 64; m <<= 1) ss += __shfl_xor(ss, m, 64);
    float kkv = kv * rsqrtf(ss + 1e-12f);
    float bbv = kkv * (1.f / (1.f + expf(-av)));
    dec[off] = d; kk[off] = kkv; bb[off] = bbv;
}

// ---------------------------------------------------------------------------
// Kernel 3: WKV-7 scan. 8 independent single-wave blocks per (b,h):
// lane = (row_local = lane&7, jg = lane>>3); lane owns S[row, jg*8 .. jg*8+8).
// 1024 waves total (1 per SIMD chip-wide). Register prefetch distance 4:
// 4 buffer sets, T-loop unrolled x4 -> each reload overlaps ~3 sub-steps of
// compute + sibling-block L2/L3 hits cover the rest of the load latency.
// Reductions across jg: shfl_xor(8,16,32).
// ---------------------------------------------------------------------------
#define LD2(dst, p) { const f32x4* _q = (const f32x4*)(p); dst[0]=_q[0]; dst[1]=_q[1]; }

__global__ __launch_bounds__(64, 1) void wkv_scan(
    const float* __restrict__ r, const float* __restrict__ k,
    const float* __restrict__ v, const float* __restrict__ dec,
    const float* __restrict__ kk, const float* __restrict__ bb,
    __hip_bfloat16* __restrict__ y) {
    const int bh = blockIdx.x >> 3;
    const int wv = blockIdx.x & 7;
    const int b = bh >> 5, h = bh & 31;
    const int lane = threadIdx.x;
    const int rlcl = lane & 7, jg = lane >> 3;
    const int row = wv * 8 + rlcl;          // state row i this lane serves
    const int jb = jg * 8;                  // j-slice base

    float S[8];
#pragma unroll
    for (int j = 0; j < 8; ++j) S[j] = 0.f;

    const size_t abase = ((size_t)b * T_ * H_ + h) * 64;
    const size_t tstep = (size_t)H_ * 64;

    f32x4 Rc[4][2], Kc[4][2], Dc[4][2], Ac[4][2], Bc[4][2];
    float vc[4];
#pragma unroll
    for (int i = 0; i < 4; ++i) {
        size_t pb = abase + (size_t)i * tstep;
        LD2(Rc[i], r   + pb + jb); LD2(Kc[i], k  + pb + jb);
        LD2(Dc[i], dec + pb + jb); LD2(Ac[i], kk + pb + jb);
        LD2(Bc[i], bb  + pb + jb); vc[i] = v[pb + row];
    }

    for (int t = 0; t < T_; t += 4) {
#pragma unroll
        for (int i = 0; i < 4; ++i) {
            const int tc = t + i;

            // sa_i = -(S_old . kk) over this lane's 8 j, reduced across jg
            float a0 = 0.f, a1 = 0.f, a2 = 0.f, a3 = 0.f;
#pragma unroll
            for (int q = 0; q < 2; ++q) {
                a0 = fmaf(S[q*4+0], Ac[i][q][0], a0);
                a1 = fmaf(S[q*4+1], Ac[i][q][1], a1);
                a2 = fmaf(S[q*4+2], Ac[i][q][2], a2);
                a3 = fmaf(S[q*4+3], Ac[i][q][3], a3);
            }
            float sum = (a0 + a1) + (a2 + a3);
            sum += __shfl_xor(sum, 8, 64);
            sum += __shfl_xor(sum, 16, 64);
            sum += __shfl_xor(sum, 32, 64);
            const float sa = -sum;

            // S = S*dec + sa*bb + v*k ;  y partial = S_new . r
            float y0 = 0.f, y1 = 0.f, y2 = 0.f, y3 = 0.f;
#pragma unroll
            for (int q = 0; q < 2; ++q) {
                {
                    float t0 = fmaf(sa, Bc[i][q][0], vc[i] * Kc[i][q][0]);
                    S[q*4+0] = fmaf(S[q*4+0], Dc[i][q][0], t0);
                    y0 = fmaf(S[q*4+0], Rc[i][q][0], y0);
                }
                {
                    float t0 = fmaf(sa, Bc[i][q][1], vc[i] * Kc[i][q][1]);
                    S[q*4+1] = fmaf(S[q*4+1], Dc[i][q][1], t0);
                    y1 = fmaf(S[q*4+1], Rc[i][q][1], y1);
                }
                {
                    float t0 = fmaf(sa, Bc[i][q][2], vc[i] * Kc[i][q][2]);
                    S[q*4+2] = fmaf(S[q*4+2], Dc[i][q][2], t0);
                    y2 = fmaf(S[q*4+2], Rc[i][q][2], y2);
                }
                {
                    float t0 = fmaf(sa, Bc[i][q][3], vc[i] * Kc[i][q][3]);
                    S[q*4+3] = fmaf(S[q*4+3], Dc[i][q][3], t0);
                    y3 = fmaf(S[q*4+3], Rc[i][q][3], y3);
                }
            }
            float ys = (y0 + y1) + (y2 + y3);
            ys += __shfl_xor(ys, 8, 64);
            ys += __shfl_xor(ys, 16, 64);
            ys += __shfl_xor(ys, 32, 64);
            if (jg == 0)
                y[((size_t)b * T_ + tc) * D_ + h * 64 + row] = __float2bfloat16(ys);

            // reload this buffer set for step tc+4 (clamped; tail reloads harmless)
            int tp = tc + 4; if (tp > T_ - 1) tp = T_ - 1;
            size_t pb = abase + (size_t)tp * tstep;
            LD2(Rc[i], r   + pb + jb); LD2(Kc[i], k  + pb + jb);
            LD2(Dc[i], dec + pb + jb); LD2(Ac[i], kk + pb + jb);
            LD2(Bc[i], bb  + pb + jb); vc[i] = v[pb + row];
        }
    }
}

// ---------------------------------------------------------------------------
// Kernel 4: C[m,o] = scale[o] * sum_d Y[m,d] * Wq[o,d]  (B^T GEMM)
// 128x128 tile, BK=64, 4 waves; global_load_lds width-16 staging (m97).
// ---------------------------------------------------------------------------
__device__ __forceinline__ void gload_lds16(const __hip_bfloat16* g, ushort* l) {
    __builtin_amdgcn_global_load_lds(
        (const __attribute__((address_space(1))) unsigned int*)g,
        (__attribute__((address_space(3))) unsigned int*)l, 16, 0, 0);
}

__global__ __launch_bounds__(256, 1) void gemm_bt(
    const __hip_bfloat16* __restrict__ A,   // [M, K]
    const __hip_bfloat16* __restrict__ Bq,  // [N, K]
    const float* __restrict__ scale,        // [N]
    float* __restrict__ C) {                // [M, N]
    const int K = D_;
    __shared__ __align__(16) ushort As[128 * 64];
    __shared__ __align__(16) ushort Bs[128 * 64];

    const int tid = threadIdx.x;
    const int lane = tid & 63;
    const int wave = tid >> 6;
    const int wr = wave >> 1, wc = wave & 1;
    const int m0 = blockIdx.x * 128;
    const int n0 = blockIdx.y * 128;

    const int srow8 = lane >> 3;
    const int scol8 = (lane & 7) * 8;
    const int ml = lane & 15;
    const int kq = (lane >> 4) * 8;

    f32x4 acc[4][4] = {};

    for (int k0 = 0; k0 < K; k0 += 64) {
#pragma unroll
        for (int c = 0; c < 4; ++c) {
            int rbase = wave * 32 + c * 8;
            int row = rbase + srow8;
            gload_lds16(A  + (size_t)(m0 + row) * K + k0 + scol8, &As[rbase * 64]);
            gload_lds16(Bq + (size_t)(n0 + row) * K + k0 + scol8, &Bs[rbase * 64]);
        }
        __syncthreads();
#pragma unroll
        for (int ks = 0; ks < 2; ++ks) {
            short8 af[4], bf[4];
#pragma unroll
            for (int tm = 0; tm < 4; ++tm)
                af[tm] = *(const short8*)(&As[(wr * 64 + tm * 16 + ml) * 64 + ks * 32 + kq]);
#pragma unroll
            for (int tn = 0; tn < 4; ++tn)
                bf[tn] = *(const short8*)(&Bs[(wc * 64 + tn * 16 + ml) * 64 + ks * 32 + kq]);
#pragma unroll
            for (int tm = 0; tm < 4; ++tm)
#pragma unroll
                for (int tn = 0; tn < 4; ++tn)
                    acc[tm][tn] = __builtin_amdgcn_mfma_f32_16x16x32_bf16(
                        af[tm], bf[tn], acc[tm][tn], 0, 0, 0);
        }
        __syncthreads();
    }

#pragma unroll
    for (int tn = 0; tn < 4; ++tn) {
        int gn = n0 + wc * 64 + tn * 16 + ml;
        float sc = scale[gn];
#pragma unroll
        for (int tm = 0; tm < 4; ++tm) {
            int gm = m0 + wr * 64 + tm * 16 + (lane >> 4) * 4;
#pragma unroll
            for (int rg = 0; rg < 4; ++rg)
                C[(size_t)(gm + rg) * D_ + gn] = acc[tm][tn][rg] * sc;
        }
    }
}

// ---------------------------------------------------------------------------
extern "C" void kernel_launch(void* const* d_in, const int* in_sizes, int n_in,
                              void* d_out, int out_size, void* d_ws, size_t ws_size,
                              hipStream_t stream) {
    (void)in_sizes; (void)n_in; (void)out_size; (void)ws_size;
    const float* r  = (const float*)d_in[0];
    const float* w  = (const float*)d_in[1];
    const float* k  = (const float*)d_in[2];
    const float* v  = (const float*)d_in[3];
    const float* ic = (const float*)d_in[4];
    const int*   wq = (const int*)d_in[5];
    const float* sc = (const float*)d_in[6];
    float* out = (float*)d_out;

    // ws layout: yb 8.4MB | wb 8.4MB | dec 16.8MB | kk 16.8MB | bb 16.8MB
    char* p = (char*)d_ws;
    __hip_bfloat16* yb = (__hip_bfloat16*)p;            p += (size_t)M_ * D_ * 2;
    __hip_bfloat16* wb = (__hip_bfloat16*)p;            p += (size_t)D_ * D_ * 2;
    float* dec = (float*)p;                             p += (size_t)B_*T_*H_*N_*4;
    float* kk  = (float*)p;                             p += (size_t)B_*T_*H_*N_*4;
    float* bb  = (float*)p;

    conv_w <<<dim3((D_ * D_) / (256 * 4)), dim3(256), 0, stream>>>(wq, wb);
    precomp<<<dim3(B_ * T_ * H_ / 4), dim3(256), 0, stream>>>(w, k, ic, dec, kk, bb);
    wkv_scan<<<dim3(B_ * H_ * 8), dim3(64), 0, stream>>>(r, k, v, dec, kk, bb, yb);
    gemm_bt<<<dim3(M_ / 128, D_ / 128), dim3(256), 0, stream>>>(yb, wb, sc, out);
}

// Round 4
// 391.348 us; speedup vs baseline: 2.4632x; 1.1203x over previous
//
#include <hip/hip_runtime.h>
#include <hip/hip_bf16.h>
#include <stdint.h>

#define B_ 4
#define T_ 512
#define H_ 32
#define N_ 64
#define D_ 2048
#define M_ (B_*T_)

typedef __attribute__((ext_vector_type(4))) float f32x4;
typedef __attribute__((ext_vector_type(8))) short short8;

// DPP butterfly add: x += lane-permuted x. Pure VALU (no LDS pipe).
template <int CTRL>
__device__ __forceinline__ float dpp_add(float x) {
    int t = __builtin_amdgcn_mov_dpp(__float_as_int(x), CTRL, 0xF, 0xF, true);
    return x + __int_as_float(t);
}
// xor1 = quad_perm[1,0,3,2]=0xB1; xor2 = quad_perm[2,3,0,1]=0x4E;
// xor4 = row_half_mirror=0x141; xor8 = row_mirror=0x140  (16-lane butterfly)
__device__ __forceinline__ float bfly16(float x) {
    x = dpp_add<0xB1>(x);
    x = dpp_add<0x4E>(x);
    x = dpp_add<0x141>(x);
    x = dpp_add<0x140>(x);
    return x;
}

// ---------------------------------------------------------------------------
// Kernel 1: dequant weights int32 -> bf16 (ints in [-128,127] exact in bf16).
// ---------------------------------------------------------------------------
__global__ __launch_bounds__(256) void conv_w(const int* __restrict__ q,
                                              __hip_bfloat16* __restrict__ o) {
    int i = (blockIdx.x * 256 + threadIdx.x) * 4;
    int4 qi = *(const int4*)(q + i);
    __hip_bfloat16 t[4];
    t[0] = __float2bfloat16((float)qi.x);
    t[1] = __float2bfloat16((float)qi.y);
    t[2] = __float2bfloat16((float)qi.z);
    t[3] = __float2bfloat16((float)qi.w);
    *(uint2*)(o + i) = *(uint2*)t;
}

// ---------------------------------------------------------------------------
// Kernel 2: precompute per-(b,t,h,channel):
//   dec = exp(-exp(w)); kk = k*rsqrt(sum_j k^2 + 1e-12); bb = kk*sigmoid(iclr)
// ---------------------------------------------------------------------------
__global__ __launch_bounds__(256) void precomp(
    const float* __restrict__ w, const float* __restrict__ k,
    const float* __restrict__ iclr,
    float* __restrict__ dec, float* __restrict__ kk, float* __restrict__ bb) {
    int g = blockIdx.x * 4 + (threadIdx.x >> 6);   // bth index
    int lane = threadIdx.x & 63;
    size_t off = (size_t)g * 64 + lane;
    float wv = w[off], kv = k[off], av = iclr[off];
    float d = expf(-expf(wv));
    float ss = kv * kv;
#pragma unroll
    for (int m = 1; m < 64; m <<= 1) ss += __shfl_xor(ss, m, 64);
    float kkv = kv * rsqrtf(ss + 1e-12f);
    float bbv = kkv * (1.f / (1.f + expf(-av)));
    dec[off] = d; kk[off] = kkv; bb[off] = bbv;
}

// ---------------------------------------------------------------------------
// Kernel 3: WKV-7 scan. 16 independent single-wave blocks per (b,h).
// lane = (jg = lane&15 [j-slice of 4 floats], rl = lane>>4 [4 rows/wave]).
// jg in LOW lane bits -> cross-jg reductions are a pure-DPP 16-lane butterfly.
// Prefetch distance 4 with SMALL sets (21 VGPR each -> ~100 total, fits; R2's
// 41-reg sets exceeded the allocator's 104 and collapsed the prefetch).
// Grid 2048 single-wave blocks = 2 waves/SIMD chip-wide.
// ---------------------------------------------------------------------------
__global__ __launch_bounds__(64, 2) void wkv_scan(
    const float* __restrict__ r, const float* __restrict__ k,
    const float* __restrict__ v, const float* __restrict__ dec,
    const float* __restrict__ kk, const float* __restrict__ bb,
    __hip_bfloat16* __restrict__ y) {
    const int bh = blockIdx.x >> 4;
    const int wv = blockIdx.x & 15;
    const int b = bh >> 5, h = bh & 31;
    const int lane = threadIdx.x;
    const int jg = lane & 15;               // j-slice base jg*4
    const int rl = lane >> 4;               // 0..3
    const int row = wv * 4 + rl;            // state row i this lane serves
    const int jb = jg * 4;

    float S[4] = {0.f, 0.f, 0.f, 0.f};

    const size_t abase = ((size_t)b * T_ * H_ + h) * 64;
    const size_t tstep = (size_t)H_ * 64;

    f32x4 Rc[4], Kc[4], Dc[4], Ac[4], Bc[4];
    float vc[4];
#pragma unroll
    for (int i = 0; i < 4; ++i) {
        size_t pb = abase + (size_t)i * tstep;
        Rc[i] = *(const f32x4*)(r   + pb + jb);
        Kc[i] = *(const f32x4*)(k   + pb + jb);
        Dc[i] = *(const f32x4*)(dec + pb + jb);
        Ac[i] = *(const f32x4*)(kk  + pb + jb);
        Bc[i] = *(const f32x4*)(bb  + pb + jb);
        vc[i] = v[pb + row];
    }

    for (int t = 0; t < T_; t += 4) {
#pragma unroll
        for (int i = 0; i < 4; ++i) {
            const int tc = t + i;

            // sa_i = -(S_old . kk): 4 in-lane FMAs + DPP butterfly over jg
            float s01 = fmaf(S[1], Ac[i][1], S[0] * Ac[i][0]);
            float s23 = fmaf(S[3], Ac[i][3], S[2] * Ac[i][2]);
            const float sa = -bfly16(s01 + s23);

            // S = S*dec + sa*bb + v*k ;  y partial = S_new . r
            float y01, y23;
            {
                float t0 = fmaf(sa, Bc[i][0], vc[i] * Kc[i][0]);
                S[0] = fmaf(S[0], Dc[i][0], t0);
                float t1 = fmaf(sa, Bc[i][1], vc[i] * Kc[i][1]);
                S[1] = fmaf(S[1], Dc[i][1], t1);
                y01 = fmaf(S[1], Rc[i][1], S[0] * Rc[i][0]);
            }
            {
                float t2 = fmaf(sa, Bc[i][2], vc[i] * Kc[i][2]);
                S[2] = fmaf(S[2], Dc[i][2], t2);
                float t3 = fmaf(sa, Bc[i][3], vc[i] * Kc[i][3]);
                S[3] = fmaf(S[3], Dc[i][3], t3);
                y23 = fmaf(S[3], Rc[i][3], S[2] * Rc[i][2]);
            }
            float ys = bfly16(y01 + y23);
            if (jg == 0)
                y[((size_t)b * T_ + tc) * D_ + h * 64 + row] = __float2bfloat16(ys);

            // reload this set for step tc+4 (clamped; tail reloads harmless)
            int tp = tc + 4; if (tp > T_ - 1) tp = T_ - 1;
            size_t pb = abase + (size_t)tp * tstep;
            Rc[i] = *(const f32x4*)(r   + pb + jb);
            Kc[i] = *(const f32x4*)(k   + pb + jb);
            Dc[i] = *(const f32x4*)(dec + pb + jb);
            Ac[i] = *(const f32x4*)(kk  + pb + jb);
            Bc[i] = *(const f32x4*)(bb  + pb + jb);
            vc[i] = v[pb + row];
        }
    }
}

// ---------------------------------------------------------------------------
// Kernel 4: C[m,o] = scale[o] * sum_d Y[m,d] * Wq[o,d]  (B^T GEMM)
// 128x128 tile, BK=64, 4 waves; global_load_lds width-16 staging (m97).
// ---------------------------------------------------------------------------
__device__ __forceinline__ void gload_lds16(const __hip_bfloat16* g, ushort* l) {
    __builtin_amdgcn_global_load_lds(
        (const __attribute__((address_space(1))) unsigned int*)g,
        (__attribute__((address_space(3))) unsigned int*)l, 16, 0, 0);
}

__global__ __launch_bounds__(256, 1) void gemm_bt(
    const __hip_bfloat16* __restrict__ A,   // [M, K]
    const __hip_bfloat16* __restrict__ Bq,  // [N, K]
    const float* __restrict__ scale,        // [N]
    float* __restrict__ C) {                // [M, N]
    const int K = D_;
    __shared__ __align__(16) ushort As[128 * 64];
    __shared__ __align__(16) ushort Bs[128 * 64];

    const int tid = threadIdx.x;
    const int lane = tid & 63;
    const int wave = tid >> 6;
    const int wr = wave >> 1, wc = wave & 1;
    const int m0 = blockIdx.x * 128;
    const int n0 = blockIdx.y * 128;

    const int srow8 = lane >> 3;
    const int scol8 = (lane & 7) * 8;
    const int ml = lane & 15;
    const int kq = (lane >> 4) * 8;

    f32x4 acc[4][4] = {};

    for (int k0 = 0; k0 < K; k0 += 64) {
#pragma unroll
        for (int c = 0; c < 4; ++c) {
            int rbase = wave * 32 + c * 8;
            int row = rbase + srow8;
            gload_lds16(A  + (size_t)(m0 + row) * K + k0 + scol8, &As[rbase * 64]);
            gload_lds16(Bq + (size_t)(n0 + row) * K + k0 + scol8, &Bs[rbase * 64]);
        }
        __syncthreads();
#pragma unroll
        for (int ks = 0; ks < 2; ++ks) {
            short8 af[4], bf[4];
#pragma unroll
            for (int tm = 0; tm < 4; ++tm)
                af[tm] = *(const short8*)(&As[(wr * 64 + tm * 16 + ml) * 64 + ks * 32 + kq]);
#pragma unroll
            for (int tn = 0; tn < 4; ++tn)
                bf[tn] = *(const short8*)(&Bs[(wc * 64 + tn * 16 + ml) * 64 + ks * 32 + kq]);
#pragma unroll
            for (int tm = 0; tm < 4; ++tm)
#pragma unroll
                for (int tn = 0; tn < 4; ++tn)
                    acc[tm][tn] = __builtin_amdgcn_mfma_f32_16x16x32_bf16(
                        af[tm], bf[tn], acc[tm][tn], 0, 0, 0);
        }
        __syncthreads();
    }

#pragma unroll
    for (int tn = 0; tn < 4; ++tn) {
        int gn = n0 + wc * 64 + tn * 16 + ml;
        float sc = scale[gn];
#pragma unroll
        for (int tm = 0; tm < 4; ++tm) {
            int gm = m0 + wr * 64 + tm * 16 + (lane >> 4) * 4;
#pragma unroll
            for (int rg = 0; rg < 4; ++rg)
                C[(size_t)(gm + rg) * D_ + gn] = acc[tm][tn][rg] * sc;
        }
    }
}

// ---------------------------------------------------------------------------
extern "C" void kernel_launch(void* const* d_in, const int* in_sizes, int n_in,
                              void* d_out, int out_size, void* d_ws, size_t ws_size,
                              hipStream_t stream) {
    (void)in_sizes; (void)n_in; (void)out_size; (void)ws_size;
    const float* r  = (const float*)d_in[0];
    const float* w  = (const float*)d_in[1];
    const float* k  = (const float*)d_in[2];
    const float* v  = (const float*)d_in[3];
    const float* ic = (const float*)d_in[4];
    const int*   wq = (const int*)d_in[5];
    const float* sc = (const float*)d_in[6];
    float* out = (float*)d_out;

    // ws layout: yb 8.4MB | wb 8.4MB | dec 16.8MB | kk 16.8MB | bb 16.8MB
    char* p = (char*)d_ws;
    __hip_bfloat16* yb = (__hip_bfloat16*)p;            p += (size_t)M_ * D_ * 2;
    __hip_bfloat16* wb = (__hip_bfloat16*)p;            p += (size_t)D_ * D_ * 2;
    float* dec = (float*)p;                             p += (size_t)B_*T_*H_*N_*4;
    float* kk  = (float*)p;                             p += (size_t)B_*T_*H_*N_*4;
    float* bb  = (float*)p;

    conv_w <<<dim3((D_ * D_) / (256 * 4)), dim3(256), 0, stream>>>(wq, wb);
    precomp<<<dim3(B_ * T_ * H_ / 4), dim3(256), 0, stream>>>(w, k, ic, dec, kk, bb);
    wkv_scan<<<dim3(B_ * H_ * 16), dim3(64), 0, stream>>>(r, k, v, dec, kk, bb, yb);
    gemm_bt<<<dim3(M_ / 128, D_ / 128), dim3(256), 0, stream>>>(yb, wb, sc, out);
}

// Round 5
// 364.531 us; speedup vs baseline: 2.6444x; 1.0736x over previous
//
#include <hip/hip_runtime.h>
#include <hip/hip_bf16.h>
#include <stdint.h>

#define B_ 4
#define T_ 512
#define H_ 32
#define N_ 64
#define D_ 2048
#define M_ (B_*T_)

typedef __attribute__((ext_vector_type(4))) float f32x4;
typedef __attribute__((ext_vector_type(8))) short short8;

// DPP butterfly add: x += lane-permuted x. Pure VALU (no LDS pipe).
template <int CTRL>
__device__ __forceinline__ float dpp_add(float x) {
    int t = __builtin_amdgcn_mov_dpp(__float_as_int(x), CTRL, 0xF, 0xF, true);
    return x + __int_as_float(t);
}
__device__ __forceinline__ float bfly16(float x) {
    x = dpp_add<0xB1>(x);    // xor1 quad_perm[1,0,3,2]
    x = dpp_add<0x4E>(x);    // xor2 quad_perm[2,3,0,1]
    x = dpp_add<0x141>(x);   // xor4 row_half_mirror
    x = dpp_add<0x140>(x);   // xor8 row_mirror
    return x;
}

// ---------------------------------------------------------------------------
// Kernel 1: dequant weights int32 -> bf16 (ints in [-128,127] exact in bf16).
// ---------------------------------------------------------------------------
__global__ __launch_bounds__(256) void conv_w(const int* __restrict__ q,
                                              __hip_bfloat16* __restrict__ o) {
    int i = (blockIdx.x * 256 + threadIdx.x) * 4;
    int4 qi = *(const int4*)(q + i);
    __hip_bfloat16 t[4];
    t[0] = __float2bfloat16((float)qi.x);
    t[1] = __float2bfloat16((float)qi.y);
    t[2] = __float2bfloat16((float)qi.z);
    t[3] = __float2bfloat16((float)qi.w);
    *(uint2*)(o + i) = *(uint2*)t;
}

// ---------------------------------------------------------------------------
// Kernel 2: precompute + TRANSPOSE to [b,h,t,c] streams:
//   dec = exp(-exp(w)); kk = k*rsqrt(sum k^2+1e-12); bb = kk*sigmoid(iclr)
//   plus straight copies of r,k,v into the same layout.
// [b,h,t,c] makes each (b,h) scan block read 6 contiguous private streams.
// ---------------------------------------------------------------------------
__global__ __launch_bounds__(256) void precomp_t(
    const float* __restrict__ r, const float* __restrict__ w,
    const float* __restrict__ k, const float* __restrict__ v,
    const float* __restrict__ iclr,
    float* __restrict__ rT, float* __restrict__ kT, float* __restrict__ vT,
    float* __restrict__ decT, float* __restrict__ kkT, float* __restrict__ bbT) {
    int g = blockIdx.x * 4 + (threadIdx.x >> 6);   // (b,t,h) flat index
    int lane = threadIdx.x & 63;
    int b = g >> 14;             // / (T*H)
    int t = (g >> 5) & (T_ - 1); // / H % T
    int h = g & 31;              // % H
    size_t si = (size_t)g * 64 + lane;
    size_t di = ((((size_t)b * H_ + h) * T_) + t) * 64 + lane;
    float rv = r[si], wv = w[si], kv = k[si], vv = v[si], av = iclr[si];
    float d = expf(-expf(wv));
    float ss = kv * kv;
#pragma unroll
    for (int m = 1; m < 64; m <<= 1) ss += __shfl_xor(ss, m, 64);
    float kkv = kv * rsqrtf(ss + 1e-12f);
    float bbv = kkv * (1.f / (1.f + expf(-av)));
    rT[di] = rv; kT[di] = kv; vT[di] = vv;
    decT[di] = d; kkT[di] = kkv; bbT[di] = bbv;
}

// ---------------------------------------------------------------------------
// Kernel 3: WKV-7 scan. 16 independent single-wave blocks per (b,h).
// lane = (jg = lane&15 [4-float j-slice], rl = lane>>4 [4 rows/wave]).
// Inputs in [b,h,t,c] layout -> 6 contiguous streams per block.
// Prefetch distance 4; asm memory-clobber at end of each sub-step PINS the
// reloads in their issue iteration (R3: compiler sank them, VGPR=60 proved it).
// ---------------------------------------------------------------------------
__global__ __launch_bounds__(64, 2) void wkv_scan(
    const float* __restrict__ rT, const float* __restrict__ kT,
    const float* __restrict__ vT, const float* __restrict__ decT,
    const float* __restrict__ kkT, const float* __restrict__ bbT,
    __hip_bfloat16* __restrict__ y) {
    const int bh = blockIdx.x >> 4;          // 0..127, = b*H + h
    const int wv = blockIdx.x & 15;
    const int b = bh >> 5, h = bh & 31;
    const int lane = threadIdx.x;
    const int jg = lane & 15;
    const int rl = lane >> 4;
    const int row = wv * 4 + rl;
    const int jb = jg * 4;

    float S[4] = {0.f, 0.f, 0.f, 0.f};

    const size_t sbase = (size_t)bh * T_ * 64;   // stream base, t-stride 64

    f32x4 Rc[4], Kc[4], Dc[4], Ac[4], Bc[4];
    float vc[4];
#pragma unroll
    for (int i = 0; i < 4; ++i) {
        size_t pb = sbase + (size_t)i * 64;
        Rc[i] = *(const f32x4*)(rT   + pb + jb);
        Kc[i] = *(const f32x4*)(kT   + pb + jb);
        Dc[i] = *(const f32x4*)(decT + pb + jb);
        Ac[i] = *(const f32x4*)(kkT  + pb + jb);
        Bc[i] = *(const f32x4*)(bbT  + pb + jb);
        vc[i] = vT[pb + row];
    }

    for (int t = 0; t < T_; t += 4) {
#pragma unroll
        for (int i = 0; i < 4; ++i) {
            const int tc = t + i;

            // sa = -(S_old . kk): 4 in-lane FMAs + DPP butterfly over jg
            float s01 = fmaf(S[1], Ac[i][1], S[0] * Ac[i][0]);
            float s23 = fmaf(S[3], Ac[i][3], S[2] * Ac[i][2]);
            const float sa = -bfly16(s01 + s23);

            // S = S*dec + sa*bb + v*k ;  y partial = S_new . r
            float t0 = fmaf(sa, Bc[i][0], vc[i] * Kc[i][0]);
            S[0] = fmaf(S[0], Dc[i][0], t0);
            float t1 = fmaf(sa, Bc[i][1], vc[i] * Kc[i][1]);
            S[1] = fmaf(S[1], Dc[i][1], t1);
            float y01 = fmaf(S[1], Rc[i][1], S[0] * Rc[i][0]);
            float t2 = fmaf(sa, Bc[i][2], vc[i] * Kc[i][2]);
            S[2] = fmaf(S[2], Dc[i][2], t2);
            float t3 = fmaf(sa, Bc[i][3], vc[i] * Kc[i][3]);
            S[3] = fmaf(S[3], Dc[i][3], t3);
            float y23 = fmaf(S[3], Rc[i][3], S[2] * Rc[i][2]);
            float ys = bfly16(y01 + y23);
            if (jg == 0)
                y[((size_t)b * T_ + tc) * D_ + h * 64 + row] = __float2bfloat16(ys);

            // reload this set for step tc+4 (clamped tail; harmless re-reads)
            int tp = tc + 4; if (tp > T_ - 1) tp = T_ - 1;
            size_t pb = sbase + (size_t)tp * 64;
            Rc[i] = *(const f32x4*)(rT   + pb + jb);
            Kc[i] = *(const f32x4*)(kT   + pb + jb);
            Dc[i] = *(const f32x4*)(decT + pb + jb);
            Ac[i] = *(const f32x4*)(kkT  + pb + jb);
            Bc[i] = *(const f32x4*)(bbT  + pb + jb);
            vc[i] = vT[pb + row];
            // PIN: loads above may not sink past this point (R3 fix).
            asm volatile("" ::: "memory");
        }
    }
}

// ---------------------------------------------------------------------------
// Kernel 4: C[m,o] = scale[o] * sum_d Y[m,d] * Wq[o,d]  (B^T GEMM)
// 128x128 tile, BK=64, 4 waves; global_load_lds width-16 staging (m97).
// ---------------------------------------------------------------------------
__device__ __forceinline__ void gload_lds16(const __hip_bfloat16* g, ushort* l) {
    __builtin_amdgcn_global_load_lds(
        (const __attribute__((address_space(1))) unsigned int*)g,
        (__attribute__((address_space(3))) unsigned int*)l, 16, 0, 0);
}

__global__ __launch_bounds__(256, 1) void gemm_bt(
    const __hip_bfloat16* __restrict__ A,   // [M, K]
    const __hip_bfloat16* __restrict__ Bq,  // [N, K]
    const float* __restrict__ scale,        // [N]
    float* __restrict__ C) {                // [M, N]
    const int K = D_;
    __shared__ __align__(16) ushort As[128 * 64];
    __shared__ __align__(16) ushort Bs[128 * 64];

    const int tid = threadIdx.x;
    const int lane = tid & 63;
    const int wave = tid >> 6;
    const int wr = wave >> 1, wc = wave & 1;
    const int m0 = blockIdx.x * 128;
    const int n0 = blockIdx.y * 128;

    const int srow8 = lane >> 3;
    const int scol8 = (lane & 7) * 8;
    const int ml = lane & 15;
    const int kq = (lane >> 4) * 8;

    f32x4 acc[4][4] = {};

    for (int k0 = 0; k0 < K; k0 += 64) {
#pragma unroll
        for (int c = 0; c < 4; ++c) {
            int rbase = wave * 32 + c * 8;
            int row = rbase + srow8;
            gload_lds16(A  + (size_t)(m0 + row) * K + k0 + scol8, &As[rbase * 64]);
            gload_lds16(Bq + (size_t)(n0 + row) * K + k0 + scol8, &Bs[rbase * 64]);
        }
        __syncthreads();
#pragma unroll
        for (int ks = 0; ks < 2; ++ks) {
            short8 af[4], bf[4];
#pragma unroll
            for (int tm = 0; tm < 4; ++tm)
                af[tm] = *(const short8*)(&As[(wr * 64 + tm * 16 + ml) * 64 + ks * 32 + kq]);
#pragma unroll
            for (int tn = 0; tn < 4; ++tn)
                bf[tn] = *(const short8*)(&Bs[(wc * 64 + tn * 16 + ml) * 64 + ks * 32 + kq]);
#pragma unroll
            for (int tm = 0; tm < 4; ++tm)
#pragma unroll
                for (int tn = 0; tn < 4; ++tn)
                    acc[tm][tn] = __builtin_amdgcn_mfma_f32_16x16x32_bf16(
                        af[tm], bf[tn], acc[tm][tn], 0, 0, 0);
        }
        __syncthreads();
    }

#pragma unroll
    for (int tn = 0; tn < 4; ++tn) {
        int gn = n0 + wc * 64 + tn * 16 + ml;
        float sc = scale[gn];
#pragma unroll
        for (int tm = 0; tm < 4; ++tm) {
            int gm = m0 + wr * 64 + tm * 16 + (lane >> 4) * 4;
#pragma unroll
            for (int rg = 0; rg < 4; ++rg)
                C[(size_t)(gm + rg) * D_ + gn] = acc[tm][tn][rg] * sc;
        }
    }
}

// ---------------------------------------------------------------------------
extern "C" void kernel_launch(void* const* d_in, const int* in_sizes, int n_in,
                              void* d_out, int out_size, void* d_ws, size_t ws_size,
                              hipStream_t stream) {
    (void)in_sizes; (void)n_in; (void)out_size; (void)ws_size;
    const float* r  = (const float*)d_in[0];
    const float* w  = (const float*)d_in[1];
    const float* k  = (const float*)d_in[2];
    const float* v  = (const float*)d_in[3];
    const float* ic = (const float*)d_in[4];
    const int*   wq = (const int*)d_in[5];
    const float* sc = (const float*)d_in[6];
    float* out = (float*)d_out;

    // ws: yb 8.4MB | wb 8.4MB | 6 transposed streams x 16.8MB (= ~118MB)
    const size_t NE = (size_t)B_ * T_ * H_ * N_;   // 4.19M elements
    char* p = (char*)d_ws;
    __hip_bfloat16* yb = (__hip_bfloat16*)p;  p += (size_t)M_ * D_ * 2;
    __hip_bfloat16* wb = (__hip_bfloat16*)p;  p += (size_t)D_ * D_ * 2;
    float* rT   = (float*)p;  p += NE * 4;
    float* kT   = (float*)p;  p += NE * 4;
    float* vT   = (float*)p;  p += NE * 4;
    float* decT = (float*)p;  p += NE * 4;
    float* kkT  = (float*)p;  p += NE * 4;
    float* bbT  = (float*)p;

    conv_w   <<<dim3((D_ * D_) / (256 * 4)), dim3(256), 0, stream>>>(wq, wb);
    precomp_t<<<dim3(B_ * T_ * H_ / 4), dim3(256), 0, stream>>>(
        r, w, k, v, ic, rT, kT, vT, decT, kkT, bbT);
    wkv_scan <<<dim3(B_ * H_ * 16), dim3(64), 0, stream>>>(
        rT, kT, vT, decT, kkT, bbT, yb);
    gemm_bt  <<<dim3(M_ / 128, D_ / 128), dim3(256), 0, stream>>>(yb, wb, sc, out);
}

// Round 6
// 352.796 us; speedup vs baseline: 2.7324x; 1.0333x over previous
//
#include <hip/hip_runtime.h>
#include <hip/hip_bf16.h>
#include <stdint.h>

#define B_ 4
#define T_ 512
#define H_ 32
#define N_ 64
#define D_ 2048
#define M_ (B_*T_)

typedef __attribute__((ext_vector_type(4))) float f32x4;
typedef __attribute__((ext_vector_type(8))) short short8;

// DPP butterfly add: x += lane-permuted x. Pure VALU (no LDS pipe).
template <int CTRL>
__device__ __forceinline__ float dpp_add(float x) {
    int t = __builtin_amdgcn_mov_dpp(__float_as_int(x), CTRL, 0xF, 0xF, true);
    return x + __int_as_float(t);
}
__device__ __forceinline__ float bfly16(float x) {
    x = dpp_add<0xB1>(x);    // xor1 quad_perm[1,0,3,2]
    x = dpp_add<0x4E>(x);    // xor2 quad_perm[2,3,0,1]
    x = dpp_add<0x141>(x);   // xor4 row_half_mirror
    x = dpp_add<0x140>(x);   // xor8 row_mirror
    return x;
}

// ---------------------------------------------------------------------------
// Kernel 1: dequant weights int32 -> bf16 (ints in [-128,127] exact in bf16).
// ---------------------------------------------------------------------------
__global__ __launch_bounds__(256) void conv_w(const int* __restrict__ q,
                                              __hip_bfloat16* __restrict__ o) {
    int i = (blockIdx.x * 256 + threadIdx.x) * 4;
    int4 qi = *(const int4*)(q + i);
    __hip_bfloat16 t[4];
    t[0] = __float2bfloat16((float)qi.x);
    t[1] = __float2bfloat16((float)qi.y);
    t[2] = __float2bfloat16((float)qi.z);
    t[3] = __float2bfloat16((float)qi.w);
    *(uint2*)(o + i) = *(uint2*)t;
}

// ---------------------------------------------------------------------------
// Kernel 2: precompute + TRANSPOSE to [b,h,t,c] streams:
//   dec = exp(-exp(w)); kk = k*rsqrt(sum k^2+1e-12); bb = kk*sigmoid(iclr)
//   plus straight copies of r,k,v into the same layout.
// ---------------------------------------------------------------------------
__global__ __launch_bounds__(256) void precomp_t(
    const float* __restrict__ r, const float* __restrict__ w,
    const float* __restrict__ k, const float* __restrict__ v,
    const float* __restrict__ iclr,
    float* __restrict__ rT, float* __restrict__ kT, float* __restrict__ vT,
    float* __restrict__ decT, float* __restrict__ kkT, float* __restrict__ bbT) {
    int g = blockIdx.x * 4 + (threadIdx.x >> 6);   // (b,t,h) flat index
    int lane = threadIdx.x & 63;
    int b = g >> 14;             // / (T*H)
    int t = (g >> 5) & (T_ - 1); // / H % T
    int h = g & 31;              // % H
    size_t si = (size_t)g * 64 + lane;
    size_t di = ((((size_t)b * H_ + h) * T_) + t) * 64 + lane;
    float rv = r[si], wv = w[si], kv = k[si], vv = v[si], av = iclr[si];
    float d = expf(-expf(wv));
    float ss = kv * kv;
#pragma unroll
    for (int m = 1; m < 64; m <<= 1) ss += __shfl_xor(ss, m, 64);
    float kkv = kv * rsqrtf(ss + 1e-12f);
    float bbv = kkv * (1.f / (1.f + expf(-av)));
    rT[di] = rv; kT[di] = kv; vT[di] = vv;
    decT[di] = d; kkT[di] = kkv; bbT[di] = bbv;
}

// ---------------------------------------------------------------------------
// Kernel 3: WKV-7 scan with LDS-ring prefetch (depth 8) via global_load_lds.
// DMA has no dest VGPRs -> the compiler cannot collapse the prefetch (R2-R4
// failure mode). Per step: issue 6 width-4 DMAs for t+8, s_waitcnt vmcnt(42)
// (6*8-6: oldest 6 = step t's loads done), ds_read 1.5KB, compute.
// lane = (jg = lane&15 [4-float j-slice], rl = lane>>4); 16 blocks/bh.
// Block swizzle: bh = id&127 -> all 16 siblings share id%8 (same XCD) for L2.
// ---------------------------------------------------------------------------
__device__ __forceinline__ void gld4(const float* g, float* l) {
    __builtin_amdgcn_global_load_lds(
        (const __attribute__((address_space(1))) unsigned int*)g,
        (__attribute__((address_space(3))) unsigned int*)l, 4, 0, 0);
}

__global__ __launch_bounds__(64, 2) void wkv_scan(
    const float* __restrict__ rT, const float* __restrict__ kT,
    const float* __restrict__ vT, const float* __restrict__ decT,
    const float* __restrict__ kkT, const float* __restrict__ bbT,
    __hip_bfloat16* __restrict__ y) {
    const int bh = blockIdx.x & 127;         // b*H + h  (XCD co-location)
    const int wv = blockIdx.x >> 7;          // 0..15 sibling index
    const int b = bh >> 5, h = bh & 31;
    const int lane = threadIdx.x;
    const int jg = lane & 15;
    const int rl = lane >> 4;
    const int row = wv * 4 + rl;
    const int jb = jg * 4;

    __shared__ float ring[8][6][64];         // 12 KB: [slot][stream][chan]

    const size_t sbase = (size_t)bh * T_ * 64;
    const float* st[6] = { rT + sbase, kT + sbase, vT + sbase,
                           decT + sbase, kkT + sbase, bbT + sbase };

    // prologue: fill all 8 slots (48 outstanding DMAs)
#pragma unroll
    for (int i = 0; i < 8; ++i)
#pragma unroll
        for (int s = 0; s < 6; ++s)
            gld4(st[s] + i * 64 + lane, &ring[i][s][0]);

    float S[4] = {0.f, 0.f, 0.f, 0.f};

    for (int t = 0; t < T_; ++t) {
        const int slot = t & 7;
        // wait until this slot's 6 DMAs have landed (oldest 6 of <=49)
        asm volatile("s_waitcnt vmcnt(42)" ::: "memory");

        f32x4 Rc = *(const f32x4*)(&ring[slot][0][jb]);
        f32x4 Kc = *(const f32x4*)(&ring[slot][1][jb]);
        float vcv =                  ring[slot][2][row];
        f32x4 Dc = *(const f32x4*)(&ring[slot][3][jb]);
        f32x4 Ac = *(const f32x4*)(&ring[slot][4][jb]);
        f32x4 Bc = *(const f32x4*)(&ring[slot][5][jb]);

        // sa = -(S_old . kk): 4 in-lane FMAs + DPP butterfly over jg
        float s01 = fmaf(S[1], Ac[1], S[0] * Ac[0]);
        float s23 = fmaf(S[3], Ac[3], S[2] * Ac[2]);
        const float sa = -bfly16(s01 + s23);

        // S = S*dec + sa*bb + v*k ;  y partial = S_new . r
        float t0 = fmaf(sa, Bc[0], vcv * Kc[0]);
        S[0] = fmaf(S[0], Dc[0], t0);
        float t1 = fmaf(sa, Bc[1], vcv * Kc[1]);
        S[1] = fmaf(S[1], Dc[1], t1);
        float y01 = fmaf(S[1], Rc[1], S[0] * Rc[0]);
        float t2 = fmaf(sa, Bc[2], vcv * Kc[2]);
        S[2] = fmaf(S[2], Dc[2], t2);
        float t3 = fmaf(sa, Bc[3], vcv * Kc[3]);
        S[3] = fmaf(S[3], Dc[3], t3);
        float y23 = fmaf(S[3], Rc[3], S[2] * Rc[2]);
        float ys = bfly16(y01 + y23);
        if (jg == 0)
            y[((size_t)b * T_ + t) * D_ + h * 64 + row] = __float2bfloat16(ys);

        // keep the ds_reads above ordered before the slot's refill below
        asm volatile("" ::: "memory");
        int tp = t + 8; if (tp > T_ - 1) tp = T_ - 1;   // tail: harmless re-read
#pragma unroll
        for (int s = 0; s < 6; ++s)
            gld4(st[s] + (size_t)tp * 64 + lane, &ring[slot][s][0]);
    }
}

// ---------------------------------------------------------------------------
// Kernel 4: C[m,o] = scale[o] * sum_d Y[m,d] * Wq[o,d]  (B^T GEMM)
// 128x128 tile, BK=64, 4 waves; global_load_lds width-16 staging (m97).
// ---------------------------------------------------------------------------
__device__ __forceinline__ void gload_lds16(const __hip_bfloat16* g, ushort* l) {
    __builtin_amdgcn_global_load_lds(
        (const __attribute__((address_space(1))) unsigned int*)g,
        (__attribute__((address_space(3))) unsigned int*)l, 16, 0, 0);
}

__global__ __launch_bounds__(256, 1) void gemm_bt(
    const __hip_bfloat16* __restrict__ A,   // [M, K]
    const __hip_bfloat16* __restrict__ Bq,  // [N, K]
    const float* __restrict__ scale,        // [N]
    float* __restrict__ C) {                // [M, N]
    const int K = D_;
    __shared__ __align__(16) ushort As[128 * 64];
    __shared__ __align__(16) ushort Bs[128 * 64];

    const int tid = threadIdx.x;
    const int lane = tid & 63;
    const int wave = tid >> 6;
    const int wr = wave >> 1, wc = wave & 1;
    const int m0 = blockIdx.x * 128;
    const int n0 = blockIdx.y * 128;

    const int srow8 = lane >> 3;
    const int scol8 = (lane & 7) * 8;
    const int ml = lane & 15;
    const int kq = (lane >> 4) * 8;

    f32x4 acc[4][4] = {};

    for (int k0 = 0; k0 < K; k0 += 64) {
#pragma unroll
        for (int c = 0; c < 4; ++c) {
            int rbase = wave * 32 + c * 8;
            int row = rbase + srow8;
            gload_lds16(A  + (size_t)(m0 + row) * K + k0 + scol8, &As[rbase * 64]);
            gload_lds16(Bq + (size_t)(n0 + row) * K + k0 + scol8, &Bs[rbase * 64]);
        }
        __syncthreads();
#pragma unroll
        for (int ks = 0; ks < 2; ++ks) {
            short8 af[4], bf[4];
#pragma unroll
            for (int tm = 0; tm < 4; ++tm)
                af[tm] = *(const short8*)(&As[(wr * 64 + tm * 16 + ml) * 64 + ks * 32 + kq]);
#pragma unroll
            for (int tn = 0; tn < 4; ++tn)
                bf[tn] = *(const short8*)(&Bs[(wc * 64 + tn * 16 + ml) * 64 + ks * 32 + kq]);
#pragma unroll
            for (int tm = 0; tm < 4; ++tm)
#pragma unroll
                for (int tn = 0; tn < 4; ++tn)
                    acc[tm][tn] = __builtin_amdgcn_mfma_f32_16x16x32_bf16(
                        af[tm], bf[tn], acc[tm][tn], 0, 0, 0);
        }
        __syncthreads();
    }

#pragma unroll
    for (int tn = 0; tn < 4; ++tn) {
        int gn = n0 + wc * 64 + tn * 16 + ml;
        float sc = scale[gn];
#pragma unroll
        for (int tm = 0; tm < 4; ++tm) {
            int gm = m0 + wr * 64 + tm * 16 + (lane >> 4) * 4;
#pragma unroll
            for (int rg = 0; rg < 4; ++rg)
                C[(size_t)(gm + rg) * D_ + gn] = acc[tm][tn][rg] * sc;
        }
    }
}

// ---------------------------------------------------------------------------
extern "C" void kernel_launch(void* const* d_in, const int* in_sizes, int n_in,
                              void* d_out, int out_size, void* d_ws, size_t ws_size,
                              hipStream_t stream) {
    (void)in_sizes; (void)n_in; (void)out_size; (void)ws_size;
    const float* r  = (const float*)d_in[0];
    const float* w  = (const float*)d_in[1];
    const float* k  = (const float*)d_in[2];
    const float* v  = (const float*)d_in[3];
    const float* ic = (const float*)d_in[4];
    const int*   wq = (const int*)d_in[5];
    const float* sc = (const float*)d_in[6];
    float* out = (float*)d_out;

    // ws: yb 8.4MB | wb 8.4MB | 6 transposed streams x 16.8MB (= ~118MB)
    const size_t NE = (size_t)B_ * T_ * H_ * N_;   // 4.19M elements
    char* p = (char*)d_ws;
    __hip_bfloat16* yb = (__hip_bfloat16*)p;  p += (size_t)M_ * D_ * 2;
    __hip_bfloat16* wb = (__hip_bfloat16*)p;  p += (size_t)D_ * D_ * 2;
    float* rT   = (float*)p;  p += NE * 4;
    float* kT   = (float*)p;  p += NE * 4;
    float* vT   = (float*)p;  p += NE * 4;
    float* decT = (float*)p;  p += NE * 4;
    float* kkT  = (float*)p;  p += NE * 4;
    float* bbT  = (float*)p;

    conv_w   <<<dim3((D_ * D_) / (256 * 4)), dim3(256), 0, stream>>>(wq, wb);
    precomp_t<<<dim3(B_ * T_ * H_ / 4), dim3(256), 0, stream>>>(
        r, w, k, v, ic, rT, kT, vT, decT, kkT, bbT);
    wkv_scan <<<dim3(B_ * H_ * 16), dim3(64), 0, stream>>>(
        rT, kT, vT, decT, kkT, bbT, yb);
    gemm_bt  <<<dim3(M_ / 128, D_ / 128), dim3(256), 0, stream>>>(yb, wb, sc, out);
}

// Round 7
// 299.186 us; speedup vs baseline: 3.2220x; 1.1792x over previous
//
#include <hip/hip_runtime.h>
#include <hip/hip_bf16.h>
#include <stdint.h>

#define B_ 4
#define T_ 512
#define H_ 32
#define N_ 64
#define D_ 2048
#define M_ (B_*T_)

typedef __attribute__((ext_vector_type(4))) float f32x4;
typedef __attribute__((ext_vector_type(8))) short short8;

// DPP butterfly add across 16-lane groups: pure VALU.
template <int CTRL>
__device__ __forceinline__ float dpp_add(float x) {
    int t = __builtin_amdgcn_mov_dpp(__float_as_int(x), CTRL, 0xF, 0xF, true);
    return x + __int_as_float(t);
}
__device__ __forceinline__ float bfly16(float x) {
    x = dpp_add<0xB1>(x);    // xor1
    x = dpp_add<0x4E>(x);    // xor2
    x = dpp_add<0x141>(x);   // xor4 row_half_mirror
    x = dpp_add<0x140>(x);   // xor8 row_mirror
    return x;
}

__device__ __forceinline__ void gld16(const float* g, float* l) {
    __builtin_amdgcn_global_load_lds(
        (const __attribute__((address_space(1))) unsigned int*)g,
        (__attribute__((address_space(3))) unsigned int*)l, 16, 0, 0);
}

// ---------------------------------------------------------------------------
// Kernel 1 (fused): blocks [0,16384): precompute+pack streams into
// pk[bh][t][6][64] (streams: r,k,v,dec,kk,bb); blocks [16384,20480): dequant
// weights int32 -> bf16 (ints in [-128,127] exact in bf16).
// ---------------------------------------------------------------------------
__global__ __launch_bounds__(256) void prep(
    const float* __restrict__ r, const float* __restrict__ w,
    const float* __restrict__ k, const float* __restrict__ v,
    const float* __restrict__ iclr, const int* __restrict__ q,
    float* __restrict__ pk, __hip_bfloat16* __restrict__ o) {
    if (blockIdx.x >= 16384) {      // ---- weight dequant part ----
        int i = ((blockIdx.x - 16384) * 256 + threadIdx.x) * 4;
        int4 qi = *(const int4*)(q + i);
        __hip_bfloat16 t[4];
        t[0] = __float2bfloat16((float)qi.x);
        t[1] = __float2bfloat16((float)qi.y);
        t[2] = __float2bfloat16((float)qi.z);
        t[3] = __float2bfloat16((float)qi.w);
        *(uint2*)(o + i) = *(uint2*)t;
        return;
    }
    // ---- precompute + transpose-pack part ----
    int g = blockIdx.x * 4 + (threadIdx.x >> 6);   // (b,t,h) flat index
    int lane = threadIdx.x & 63;
    int b = g >> 14;             // / (T*H)
    int t = (g >> 5) & (T_ - 1); // / H % T
    int h = g & 31;              // % H
    size_t si = (size_t)g * 64 + lane;
    size_t di = (((size_t)(b * H_ + h) * T_) + t) * 384 + lane;  // stream 0 chan
    float rv = r[si], wv = w[si], kv = k[si], vv = v[si], av = iclr[si];
    float d = expf(-expf(wv));
    float ss = kv * kv;
#pragma unroll
    for (int m = 1; m < 64; m <<= 1) ss += __shfl_xor(ss, m, 64);
    float kkv = kv * rsqrtf(ss + 1e-12f);
    float bbv = kkv * (1.f / (1.f + expf(-av)));
    pk[di          ] = rv;
    pk[di + 1 * 64 ] = kv;
    pk[di + 2 * 64 ] = vv;
    pk[di + 3 * 64 ] = d;
    pk[di + 4 * 64 ] = kkv;
    pk[di + 5 * 64 ] = bbv;
}

// ---------------------------------------------------------------------------
// Kernel 2: WKV-7 scan, packed-stream LDS ring.
// 16 single-wave blocks per (b,h); lane = (jg = lane&15, rl = lane>>4),
// lane owns S[row = wv*4+rl, jg*4 .. jg*4+4).
// Ring: 2 superslots x 4 steps x 1536B = 12KB. Refill = 6 width-16 DMAs per
// 4 steps (amortized 1.5/step; R5 paid 6/step + 6 addr chains).
// vmcnt accounting: group = 6 DMA + 4 y-stores; steady wait vmcnt(10)
// guarantees the 2-groups-old refill landed; g=0 peeled at vmcnt(6).
// Swizzle bh = id&127 keeps all 16 siblings on one XCD (R5: FETCH 406->68MB).
// ---------------------------------------------------------------------------
__global__ __launch_bounds__(64, 2) void wkv_scan(
    const float* __restrict__ pk, __hip_bfloat16* __restrict__ y) {
    const int bh = blockIdx.x & 127;
    const int wv = blockIdx.x >> 7;
    const int b = bh >> 5, h = bh & 31;
    const int lane = threadIdx.x;
    const int jg = lane & 15;
    const int rl = lane >> 4;
    const int row = wv * 4 + rl;

    __shared__ __align__(16) float ring[2 * 1536];   // 12 KB

    const float* src = pk + (size_t)bh * T_ * 384;

    // prologue: fill both superslots (12 DMAs outstanding)
#pragma unroll
    for (int gg = 0; gg < 2; ++gg) {
        const float* g0 = src + (size_t)gg * 1536 + lane * 4;
        float* l0 = &ring[gg * 1536];
#pragma unroll
        for (int c = 0; c < 6; ++c)
            gld16(g0 + c * 256, l0 + c * 256);
    }

    float S[4] = {0.f, 0.f, 0.f, 0.f};

    for (int g = 0; g < T_ / 4; ++g) {
        const int slot = g & 1;
        if (g == 0) { asm volatile("s_waitcnt vmcnt(6)"  ::: "memory"); }
        else        { asm volatile("s_waitcnt vmcnt(10)" ::: "memory"); }
        const float* rb0 = &ring[slot * 1536];

#pragma unroll
        for (int i = 0; i < 4; ++i) {
            const int t = g * 4 + i;
            const float* rb = rb0 + i * 384;

            f32x4 Rc = *(const f32x4*)(rb + 0 * 64 + jg * 4);
            f32x4 Kc = *(const f32x4*)(rb + 1 * 64 + jg * 4);
            float vcv =                 rb[2 * 64 + row];
            f32x4 Dc = *(const f32x4*)(rb + 3 * 64 + jg * 4);
            f32x4 Ac = *(const f32x4*)(rb + 4 * 64 + jg * 4);
            f32x4 Bc = *(const f32x4*)(rb + 5 * 64 + jg * 4);

            // sa = -(S_old . kk)
            float s01 = fmaf(S[1], Ac[1], S[0] * Ac[0]);
            float s23 = fmaf(S[3], Ac[3], S[2] * Ac[2]);
            const float sa = -bfly16(s01 + s23);

            // S = S*dec + sa*bb + v*k ;  y partial = S_new . r
            float t0 = fmaf(sa, Bc[0], vcv * Kc[0]);
            S[0] = fmaf(S[0], Dc[0], t0);
            float t1 = fmaf(sa, Bc[1], vcv * Kc[1]);
            S[1] = fmaf(S[1], Dc[1], t1);
            float y01 = fmaf(S[1], Rc[1], S[0] * Rc[0]);
            float t2 = fmaf(sa, Bc[2], vcv * Kc[2]);
            S[2] = fmaf(S[2], Dc[2], t2);
            float t3 = fmaf(sa, Bc[3], vcv * Kc[3]);
            S[3] = fmaf(S[3], Dc[3], t3);
            float y23 = fmaf(S[3], Rc[3], S[2] * Rc[2]);
            float ys = bfly16(y01 + y23);
            if (jg == 0)
                y[((size_t)b * T_ + t) * D_ + h * 64 + row] = __float2bfloat16(ys);
        }

        // refill this slot with group g+2 (clamped tail re-reads: harmless)
        asm volatile("" ::: "memory");
        int gp = g + 2; if (gp > T_ / 4 - 1) gp = T_ / 4 - 1;
        const float* g0 = src + (size_t)gp * 1536 + lane * 4;
        float* l0 = &ring[slot * 1536];
#pragma unroll
        for (int c = 0; c < 6; ++c)
            gld16(g0 + c * 256, l0 + c * 256);
    }
}

// ---------------------------------------------------------------------------
// Kernel 3: C[m,o] = scale[o] * sum_d Y[m,d] * Wq[o,d]  (B^T GEMM)
// 128x128 tile, BK=64, 4 waves; global_load_lds width-16 staging (m97).
// ---------------------------------------------------------------------------
__device__ __forceinline__ void gload_lds16(const __hip_bfloat16* g, ushort* l) {
    __builtin_amdgcn_global_load_lds(
        (const __attribute__((address_space(1))) unsigned int*)g,
        (__attribute__((address_space(3))) unsigned int*)l, 16, 0, 0);
}

__global__ __launch_bounds__(256, 1) void gemm_bt(
    const __hip_bfloat16* __restrict__ A,   // [M, K]
    const __hip_bfloat16* __restrict__ Bq,  // [N, K]
    const float* __restrict__ scale,        // [N]
    float* __restrict__ C) {                // [M, N]
    const int K = D_;
    __shared__ __align__(16) ushort As[128 * 64];
    __shared__ __align__(16) ushort Bs[128 * 64];

    const int tid = threadIdx.x;
    const int lane = tid & 63;
    const int wave = tid >> 6;
    const int wr = wave >> 1, wc = wave & 1;
    const int m0 = blockIdx.x * 128;
    const int n0 = blockIdx.y * 128;

    const int srow8 = lane >> 3;
    const int scol8 = (lane & 7) * 8;
    const int ml = lane & 15;
    const int kq = (lane >> 4) * 8;

    f32x4 acc[4][4] = {};

    for (int k0 = 0; k0 < K; k0 += 64) {
#pragma unroll
        for (int c = 0; c < 4; ++c) {
            int rbase = wave * 32 + c * 8;
            int row = rbase + srow8;
            gload_lds16(A  + (size_t)(m0 + row) * K + k0 + scol8, &As[rbase * 64]);
            gload_lds16(Bq + (size_t)(n0 + row) * K + k0 + scol8, &Bs[rbase * 64]);
        }
        __syncthreads();
#pragma unroll
        for (int ks = 0; ks < 2; ++ks) {
            short8 af[4], bf[4];
#pragma unroll
            for (int tm = 0; tm < 4; ++tm)
                af[tm] = *(const short8*)(&As[(wr * 64 + tm * 16 + ml) * 64 + ks * 32 + kq]);
#pragma unroll
            for (int tn = 0; tn < 4; ++tn)
                bf[tn] = *(const short8*)(&Bs[(wc * 64 + tn * 16 + ml) * 64 + ks * 32 + kq]);
#pragma unroll
            for (int tm = 0; tm < 4; ++tm)
#pragma unroll
                for (int tn = 0; tn < 4; ++tn)
                    acc[tm][tn] = __builtin_amdgcn_mfma_f32_16x16x32_bf16(
                        af[tm], bf[tn], acc[tm][tn], 0, 0, 0);
        }
        __syncthreads();
    }

#pragma unroll
    for (int tn = 0; tn < 4; ++tn) {
        int gn = n0 + wc * 64 + tn * 16 + ml;
        float sc = scale[gn];
#pragma unroll
        for (int tm = 0; tm < 4; ++tm) {
            int gm = m0 + wr * 64 + tm * 16 + (lane >> 4) * 4;
#pragma unroll
            for (int rg = 0; rg < 4; ++rg)
                C[(size_t)(gm + rg) * D_ + gn] = acc[tm][tn][rg] * sc;
        }
    }
}

// ---------------------------------------------------------------------------
extern "C" void kernel_launch(void* const* d_in, const int* in_sizes, int n_in,
                              void* d_out, int out_size, void* d_ws, size_t ws_size,
                              hipStream_t stream) {
    (void)in_sizes; (void)n_in; (void)out_size; (void)ws_size;
    const float* r  = (const float*)d_in[0];
    const float* w  = (const float*)d_in[1];
    const float* k  = (const float*)d_in[2];
    const float* v  = (const float*)d_in[3];
    const float* ic = (const float*)d_in[4];
    const int*   wq = (const int*)d_in[5];
    const float* sc = (const float*)d_in[6];
    float* out = (float*)d_out;

    // ws: yb 8.4MB | wb 8.4MB | pk (packed streams) 100.7MB  (~118 MB total)
    char* p = (char*)d_ws;
    __hip_bfloat16* yb = (__hip_bfloat16*)p;  p += (size_t)M_ * D_ * 2;
    __hip_bfloat16* wb = (__hip_bfloat16*)p;  p += (size_t)D_ * D_ * 2;
    float* pk = (float*)p;

    prep    <<<dim3(16384 + 4096), dim3(256), 0, stream>>>(r, w, k, v, ic, wq, pk, wb);
    wkv_scan<<<dim3(B_ * H_ * 16), dim3(64), 0, stream>>>(pk, yb);
    gemm_bt <<<dim3(M_ / 128, D_ / 128), dim3(256), 0, stream>>>(yb, wb, sc, out);
}